// Round 1
// baseline (450.153 us; speedup 1.0000x reference)
//
#include <hip/hip_runtime.h>
#include <math.h>

// Sizes
#define NB 32
#define NT 1024
#define ND 128     // D_IN
#define NK 256     // D_HID
#define NO 128     // D_OUT
#define NF 513     // NT/2 + 1

__device__ __forceinline__ unsigned brev10(unsigned j) { return __brev(j) >> 22; }

// ---------------- forward rfft along time axis ----------------
// One workgroup handles 8 channels (d0..d0+7) of one batch b: 8 complex FFTs of
// length 1024 in LDS (radix-2 DIT). wave g (64 lanes) owns FFT g.
__global__ __launch_bounds__(512) void rfft_kernel(const float* __restrict__ x,
                                                   float* __restrict__ Xre,
                                                   float* __restrict__ Xim) {
  __shared__ float2 a[8 * 1024];   // 64 KB
  __shared__ float2 tw[512];       // 4 KB
  const int tid = threadIdx.x;
  const int b = blockIdx.x >> 4;
  const int d0 = (blockIdx.x & 15) << 3;
  {
    float s, c;
    sincosf(6.283185307179586f * (float)tid / 1024.0f, &s, &c);
    if (tid < 512) tw[tid] = make_float2(c, -s);   // exp(-2*pi*i*k/N)
  }
  const float* xb = x + (size_t)b * NT * ND + d0;
  for (int idx = tid; idx < 8192; idx += 512) {
    int t = idx >> 3, dd = idx & 7;
    a[dd * 1024 + t] = make_float2(xb[t * ND + dd], 0.0f);
  }
  __syncthreads();
  const int g = tid >> 6, l = tid & 63;
  float2* ag = a + g * 1024;
  for (int j = l; j < 1024; j += 64) {
    int r = (int)brev10((unsigned)j);
    if (j < r) { float2 t0 = ag[j]; ag[j] = ag[r]; ag[r] = t0; }
  }
  __syncthreads();
  for (int s = 0; s < 10; ++s) {
    const int half = 1 << s;
    for (int j = l; j < 512; j += 64) {
      int pos = j & (half - 1);
      int i0 = ((j >> s) << (s + 1)) + pos;
      int i1 = i0 + half;
      float2 w = tw[pos << (9 - s)];
      float2 u = ag[i0], v = ag[i1];
      float tr = w.x * v.x - w.y * v.y;
      float ti = w.x * v.y + w.y * v.x;
      ag[i1] = make_float2(u.x - tr, u.y - ti);
      ag[i0] = make_float2(u.x + tr, u.y + ti);
    }
    __syncthreads();
  }
  float* Xrb = Xre + (size_t)b * NF * ND + d0;
  float* Xib = Xim + (size_t)b * NF * ND + d0;
  for (int idx = tid; idx < NF * 8; idx += 512) {
    int f = idx >> 3, dd = idx & 7;
    float2 v = a[dd * 1024 + f];
    Xrb[(size_t)f * ND + dd] = v.x;
    Xib[(size_t)f * ND + dd] = v.y;
  }
}

// ---------------- per-frequency complex MLP ----------------
// One workgroup per frequency f. 512 threads: n = tid&255 output column,
// bh = tid>>8 selects 16 of the 32 batch rows. X (32x128 complex) in LDS,
// accumulators in registers, W streamed from global (read exactly once).
__global__ __launch_bounds__(512) void freq_kernel(const float* __restrict__ Xre,
                                                   const float* __restrict__ Xim,
                                                   const float* __restrict__ Wre,
                                                   const float* __restrict__ Wim,
                                                   const float* __restrict__ Bre,
                                                   const float* __restrict__ Bim,
                                                   float* __restrict__ Fre,
                                                   float* __restrict__ Fim) {
  __shared__ float2 xs[NB * ND];   // 32 KB
  const int tid = threadIdx.x;
  const int f = blockIdx.x;
  const int n = tid & 255;
  const int bh = tid >> 8;         // 0 or 1
  for (int idx = tid; idx < NB * ND; idx += 512) {
    int b = idx >> 7, i = idx & 127;
    size_t off = ((size_t)b * NF + f) * ND + i;
    xs[idx] = make_float2(Xre[off], Xim[off]);
  }
  __syncthreads();
  float accR[16], accI[16];
  const float br = Bre[(size_t)f * NK + n];
  const float bi = Bim[(size_t)f * NK + n];
#pragma unroll
  for (int j = 0; j < 16; ++j) { accR[j] = br; accI[j] = bi; }
  const float* Wr = Wre + (size_t)f * ND * NK + n;
  const float* Wi = Wim + (size_t)f * ND * NK + n;
  const int base = bh * 16 * ND;
  for (int i = 0; i < ND; ++i) {
    float wr = Wr[(size_t)i * NK];
    float wi = Wi[(size_t)i * NK];
#pragma unroll
    for (int j = 0; j < 16; ++j) {
      float2 xv = xs[base + j * ND + i];
      accR[j] = fmaf(xv.x, wr, accR[j]);
      accR[j] = fmaf(-xv.y, wi, accR[j]);
      accI[j] = fmaf(xv.x, wi, accI[j]);
      accI[j] = fmaf(xv.y, wr, accI[j]);
    }
  }
#pragma unroll
  for (int j = 0; j < 16; ++j) {
    int b = bh * 16 + j;
    size_t off = ((size_t)b * NF + f) * NK + n;
    Fre[off] = fmaxf(accR[j], 0.0f);
    Fim[off] = fmaxf(accI[j], 0.0f);
  }
}

// ---------------- inverse rfft + accumulate into y ----------------
// One workgroup handles 8 hidden channels (k0..k0+7) of one batch b.
// Hermitian-extend 513 bins to 1024, inverse FFT, add real/1024 into y
// (y already holds x @ W_rc).
__global__ __launch_bounds__(512) void irfft_kernel(const float* __restrict__ Fre,
                                                    const float* __restrict__ Fim,
                                                    float* __restrict__ y) {
  __shared__ float2 a[8 * 1024];
  __shared__ float2 tw[512];
  const int tid = threadIdx.x;
  const int b = blockIdx.x >> 5;
  const int k0 = (blockIdx.x & 31) << 3;
  {
    float s, c;
    sincosf(6.283185307179586f * (float)tid / 1024.0f, &s, &c);
    if (tid < 512) tw[tid] = make_float2(c, s);    // exp(+2*pi*i*k/N)
  }
  for (int idx = tid; idx < NF * 8; idx += 512) {
    int f = idx >> 3, kk = idx & 7;
    size_t off = ((size_t)b * NF + f) * NK + k0 + kk;
    a[kk * 1024 + f] = make_float2(Fre[off], Fim[off]);
  }
  __syncthreads();
  for (int idx = tid; idx < 511 * 8; idx += 512) {
    int f = 513 + (idx >> 3), kk = idx & 7;
    float2 v = a[kk * 1024 + (1024 - f)];
    a[kk * 1024 + f] = make_float2(v.x, -v.y);
  }
  __syncthreads();
  const int g = tid >> 6, l = tid & 63;
  float2* ag = a + g * 1024;
  for (int j = l; j < 1024; j += 64) {
    int r = (int)brev10((unsigned)j);
    if (j < r) { float2 t0 = ag[j]; ag[j] = ag[r]; ag[r] = t0; }
  }
  __syncthreads();
  for (int s = 0; s < 10; ++s) {
    const int half = 1 << s;
    for (int j = l; j < 512; j += 64) {
      int pos = j & (half - 1);
      int i0 = ((j >> s) << (s + 1)) + pos;
      int i1 = i0 + half;
      float2 w = tw[pos << (9 - s)];
      float2 u = ag[i0], v = ag[i1];
      float tr = w.x * v.x - w.y * v.y;
      float ti = w.x * v.y + w.y * v.x;
      ag[i1] = make_float2(u.x - tr, u.y - ti);
      ag[i0] = make_float2(u.x + tr, u.y + ti);
    }
    __syncthreads();
  }
  float* yb = y + (size_t)b * NT * NK + k0;
  const float sc = 1.0f / 1024.0f;
  for (int idx = tid; idx < 8192; idx += 512) {
    int t = idx >> 3, kk = idx & 7;
    yb[(size_t)t * NK + kk] += a[kk * 1024 + t].x * sc;
  }
}

// ---------------- generic row-block linear layer ----------------
// C[M x N] = act(A[M x K] @ W[K x N] + bias). One workgroup = 32 rows.
// MODE 0: plain store, 1: bias + leaky-relu(0.01), 2: bias only.
template <int K, int N, int MODE>
__global__ __launch_bounds__(256) void lin_kernel(const float* __restrict__ A,
                                                  const float* __restrict__ W,
                                                  const float* __restrict__ bias,
                                                  float* __restrict__ C) {
  constexpr int GR = 256 / N;     // row groups per block
  constexpr int RPT = 32 / GR;    // rows per thread
  __shared__ __align__(16) float as[32 * K];
  const int tid = threadIdx.x;
  const int row0 = blockIdx.x * 32;
  const int n = tid % N;
  const int rs = tid / N;
  const float4* A4 = (const float4*)(A + (size_t)row0 * K);
  float4* as4 = (float4*)as;
  for (int q = tid; q < 32 * K / 4; q += 256) as4[q] = A4[q];
  __syncthreads();
  float acc[RPT];
#pragma unroll
  for (int r = 0; r < RPT; ++r) acc[r] = 0.0f;
  for (int i0 = 0; i0 < K; i0 += 4) {
    float w0 = W[(size_t)(i0 + 0) * N + n];
    float w1 = W[(size_t)(i0 + 1) * N + n];
    float w2 = W[(size_t)(i0 + 2) * N + n];
    float w3 = W[(size_t)(i0 + 3) * N + n];
#pragma unroll
    for (int r = 0; r < RPT; ++r) {
      float4 xa = as4[(rs * RPT + r) * (K / 4) + (i0 >> 2)];
      acc[r] = fmaf(xa.x, w0, acc[r]);
      acc[r] = fmaf(xa.y, w1, acc[r]);
      acc[r] = fmaf(xa.z, w2, acc[r]);
      acc[r] = fmaf(xa.w, w3, acc[r]);
    }
  }
#pragma unroll
  for (int r = 0; r < RPT; ++r) {
    float v = acc[r];
    if (MODE >= 1) v += bias[n];
    if (MODE == 1) v = (v > 0.0f) ? v : 0.01f * v;
    C[(size_t)(row0 + rs * RPT + r) * N + n] = v;
  }
}

extern "C" void kernel_launch(void* const* d_in, const int* in_sizes, int n_in,
                              void* d_out, int out_size, void* d_ws, size_t ws_size,
                              hipStream_t stream) {
  const float* x     = (const float*)d_in[0];
  const float* W_re  = (const float*)d_in[1];
  const float* W_im  = (const float*)d_in[2];
  const float* B_re  = (const float*)d_in[3];
  const float* B_im  = (const float*)d_in[4];
  const float* W_rc  = (const float*)d_in[5];
  const float* fc1_w = (const float*)d_in[6];
  const float* fc1_b = (const float*)d_in[7];
  const float* fc2_w = (const float*)d_in[8];
  const float* fc2_b = (const float*)d_in[9];
  float* out = (float*)d_out;

  // Workspace layout (floats). Total 20,996,096 floats = 80.1 MiB.
  float* ws = (float*)d_ws;
  const size_t SZ_X = (size_t)NB * NF * ND;  // 2,101,248
  const size_t SZ_F = (size_t)NB * NF * NK;  // 4,202,496
  const size_t SZ_Y = (size_t)NB * NT * NK;  // 8,388,608
  float* Xre = ws;
  float* Xim = Xre + SZ_X;
  float* Fre = Xim + SZ_X;
  float* Fim = Fre + SZ_F;
  float* y   = Fim + SZ_F;
  float* h   = ws;  // reuse: X/F regions are dead after irfft

  // 1) rfft of x along time
  rfft_kernel<<<dim3(NB * 16), dim3(512), 0, stream>>>(x, Xre, Xim);
  // 2) per-frequency complex MLP + split-ReLU
  freq_kernel<<<dim3(NF), dim3(512), 0, stream>>>(Xre, Xim, W_re, W_im, B_re, B_im, Fre, Fim);
  // 3) residual projection: y = x @ W_rc
  lin_kernel<ND, NK, 0><<<dim3((NB * NT) / 32), dim3(256), 0, stream>>>(x, W_rc, nullptr, y);
  // 4) irfft, accumulate into y
  irfft_kernel<<<dim3(NB * 32), dim3(512), 0, stream>>>(Fre, Fim, y);
  // 5) fc1 + leaky relu
  lin_kernel<NK, NK, 1><<<dim3((NB * NT) / 32), dim3(256), 0, stream>>>(y, fc1_w, fc1_b, h);
  // 6) fc2 + bias -> out
  lin_kernel<NK, NO, 2><<<dim3((NB * NT) / 32), dim3(256), 0, stream>>>(h, fc2_w, fc2_b, out);
}

// Round 2
// 345.135 us; speedup vs baseline: 1.3043x; 1.3043x over previous
//
#include <hip/hip_runtime.h>
#include <math.h>

// Sizes
#define NB 32
#define NT 1024
#define ND 128     // D_IN
#define NK 256     // D_HID
#define NO 128     // D_OUT
#define NF 513     // NT/2 + 1

typedef __attribute__((ext_vector_type(8))) short bf16x8;
typedef __attribute__((ext_vector_type(4))) float f32x4;

__device__ __forceinline__ unsigned brev10(unsigned j) { return __brev(j) >> 22; }

__device__ __forceinline__ unsigned short f2bf(float f) {
  union { float f; unsigned u; } v; v.f = f;
  return (unsigned short)((v.u + 0x7fffu + ((v.u >> 16) & 1u)) >> 16);
}
__device__ __forceinline__ float bf2f(unsigned u) {
  union { unsigned u; float f; } v; v.u = u << 16;
  return v.f;
}
__device__ __forceinline__ unsigned packbf(float re, float im) {
  return (unsigned)f2bf(re) | ((unsigned)f2bf(im) << 16);
}

// ---------------- forward rfft along time axis ----------------
// One workgroup: 8 channels (d0..d0+7) of one batch b; 8 radix-2 FFTs of 1024
// in LDS, one per wave. Output: packed bf16 (re,im) per (b,f,d).
__global__ __launch_bounds__(512) void rfft_kernel(const float* __restrict__ x,
                                                   unsigned* __restrict__ Xc) {
  __shared__ float2 a[8 * 1024];   // 64 KB
  __shared__ float2 tw[512];       // 4 KB
  const int tid = threadIdx.x;
  const int b = blockIdx.x >> 4;
  const int d0 = (blockIdx.x & 15) << 3;
  {
    float s, c;
    sincosf(6.283185307179586f * (float)tid / 1024.0f, &s, &c);
    if (tid < 512) tw[tid] = make_float2(c, -s);   // exp(-2*pi*i*k/N)
  }
  const float* xb = x + (size_t)b * NT * ND + d0;
  for (int idx = tid; idx < 8192; idx += 512) {
    int t = idx >> 3, dd = idx & 7;
    a[dd * 1024 + t] = make_float2(xb[t * ND + dd], 0.0f);
  }
  __syncthreads();
  const int g = tid >> 6, l = tid & 63;
  float2* ag = a + g * 1024;
  for (int j = l; j < 1024; j += 64) {
    int r = (int)brev10((unsigned)j);
    if (j < r) { float2 t0 = ag[j]; ag[j] = ag[r]; ag[r] = t0; }
  }
  __syncthreads();
  for (int s = 0; s < 10; ++s) {
    const int half = 1 << s;
    for (int j = l; j < 512; j += 64) {
      int pos = j & (half - 1);
      int i0 = ((j >> s) << (s + 1)) + pos;
      int i1 = i0 + half;
      float2 w = tw[pos << (9 - s)];
      float2 u = ag[i0], v = ag[i1];
      float tr = w.x * v.x - w.y * v.y;
      float ti = w.x * v.y + w.y * v.x;
      ag[i1] = make_float2(u.x - tr, u.y - ti);
      ag[i0] = make_float2(u.x + tr, u.y + ti);
    }
    __syncthreads();
  }
  unsigned* Xb = Xc + (size_t)b * NF * ND + d0;
  for (int idx = tid; idx < NF * 8; idx += 512) {
    int f = idx >> 3, dd = idx & 7;
    float2 v = a[dd * 1024 + f];
    Xb[(size_t)f * ND + dd] = packbf(v.x, v.y);
  }
}

// ---------------- per-frequency complex MLP (bf16 MFMA) ----------------
// One workgroup per frequency. 8 waves; wave w owns output cols [32w,32w+32).
// accR = Xre*Wre + (-Xim)*Wim + Bre ; accI = Xre*Wim + Xim*Wre + Bim.
// X staged in LDS bf16 with XOR-swizzled 16B blocks for conflict-free
// ds_read_b128 fragments; W read once from global, coalesced, cvt to bf16.
__global__ __launch_bounds__(512) void freq_mfma_kernel(
    const unsigned* __restrict__ Xc, const float* __restrict__ Wre,
    const float* __restrict__ Wim, const float* __restrict__ Bre,
    const float* __restrict__ Bim, unsigned* __restrict__ Fc) {
  __shared__ unsigned short Xr_l[NB * ND], Xi_l[NB * ND], Xn_l[NB * ND]; // 24 KB
  const int tid = threadIdx.x;
  const int f = blockIdx.x;
#pragma unroll
  for (int it = 0; it < 8; ++it) {
    int idx = it * 512 + tid;
    int d = idx & 127, b = idx >> 7;
    unsigned p = Xc[((size_t)b * NF + f) * ND + d];
    int off = b * 128 + ((((d >> 3) ^ (b & 15))) << 3) + (d & 7);
    unsigned short re = (unsigned short)(p & 0xffff);
    unsigned short im = (unsigned short)(p >> 16);
    Xr_l[off] = re; Xi_l[off] = im; Xn_l[off] = im ^ 0x8000;
  }
  __syncthreads();
  const int wv = tid >> 6, l = tid & 63;
  const int lr = l & 15, lg = l >> 4;
  const int n0 = wv * 32;
  f32x4 aR[2][2], aI[2][2];
#pragma unroll
  for (int nt = 0; nt < 2; ++nt) {
    float br = Bre[(size_t)f * NK + n0 + nt * 16 + lr];
    float bi = Bim[(size_t)f * NK + n0 + nt * 16 + lr];
#pragma unroll
    for (int m = 0; m < 2; ++m) {
      aR[m][nt] = (f32x4){br, br, br, br};
      aI[m][nt] = (f32x4){bi, bi, bi, bi};
    }
  }
#pragma unroll 2
  for (int ks = 0; ks < 4; ++ks) {
    bf16x8 xr[2], xi[2], xn[2];
#pragma unroll
    for (int m = 0; m < 2; ++m) {
      int row = m * 16 + lr;
      int off = row * 128 + (((ks * 4 + lg) ^ lr) << 3);
      xr[m] = *(const bf16x8*)&Xr_l[off];
      xi[m] = *(const bf16x8*)&Xi_l[off];
      xn[m] = *(const bf16x8*)&Xn_l[off];
    }
#pragma unroll
    for (int nt = 0; nt < 2; ++nt) {
      int col = n0 + nt * 16 + lr;
      const float* wr = Wre + ((size_t)f * ND + ks * 32 + lg * 8) * NK + col;
      const float* wi = Wim + ((size_t)f * ND + ks * 32 + lg * 8) * NK + col;
      bf16x8 bR, bI;
#pragma unroll
      for (int j = 0; j < 8; ++j) {
        bR[j] = (short)f2bf(wr[(size_t)j * NK]);
        bI[j] = (short)f2bf(wi[(size_t)j * NK]);
      }
#pragma unroll
      for (int m = 0; m < 2; ++m) {
        aR[m][nt] = __builtin_amdgcn_mfma_f32_16x16x32_bf16(xr[m], bR, aR[m][nt], 0, 0, 0);
        aR[m][nt] = __builtin_amdgcn_mfma_f32_16x16x32_bf16(xn[m], bI, aR[m][nt], 0, 0, 0);
        aI[m][nt] = __builtin_amdgcn_mfma_f32_16x16x32_bf16(xr[m], bI, aI[m][nt], 0, 0, 0);
        aI[m][nt] = __builtin_amdgcn_mfma_f32_16x16x32_bf16(xi[m], bR, aI[m][nt], 0, 0, 0);
      }
    }
  }
  // epilogue: split-ReLU, pack bf16, store. D layout: col=lane&15, row=(lane>>4)*4+r
#pragma unroll
  for (int m = 0; m < 2; ++m)
#pragma unroll
    for (int nt = 0; nt < 2; ++nt)
#pragma unroll
      for (int r = 0; r < 4; ++r) {
        int brow = m * 16 + lg * 4 + r;
        int col = n0 + nt * 16 + lr;
        float vR = fmaxf(aR[m][nt][r], 0.0f);
        float vI = fmaxf(aI[m][nt][r], 0.0f);
        Fc[((size_t)brow * NF + f) * NK + col] = packbf(vR, vI);
      }
}

// ---------------- inverse rfft + accumulate into y ----------------
__global__ __launch_bounds__(512) void irfft_kernel(const unsigned* __restrict__ Fc,
                                                    float* __restrict__ y) {
  __shared__ float2 a[8 * 1024];
  __shared__ float2 tw[512];
  const int tid = threadIdx.x;
  const int b = blockIdx.x >> 5;
  const int k0 = (blockIdx.x & 31) << 3;
  {
    float s, c;
    sincosf(6.283185307179586f * (float)tid / 1024.0f, &s, &c);
    if (tid < 512) tw[tid] = make_float2(c, s);    // exp(+2*pi*i*k/N)
  }
  for (int idx = tid; idx < NF * 8; idx += 512) {
    int f = idx >> 3, kk = idx & 7;
    unsigned p = Fc[((size_t)b * NF + f) * NK + k0 + kk];
    a[kk * 1024 + f] = make_float2(bf2f(p & 0xffff), bf2f(p >> 16));
  }
  __syncthreads();
  for (int idx = tid; idx < 511 * 8; idx += 512) {
    int f = 513 + (idx >> 3), kk = idx & 7;
    float2 v = a[kk * 1024 + (1024 - f)];
    a[kk * 1024 + f] = make_float2(v.x, -v.y);
  }
  __syncthreads();
  const int g = tid >> 6, l = tid & 63;
  float2* ag = a + g * 1024;
  for (int j = l; j < 1024; j += 64) {
    int r = (int)brev10((unsigned)j);
    if (j < r) { float2 t0 = ag[j]; ag[j] = ag[r]; ag[r] = t0; }
  }
  __syncthreads();
  for (int s = 0; s < 10; ++s) {
    const int half = 1 << s;
    for (int j = l; j < 512; j += 64) {
      int pos = j & (half - 1);
      int i0 = ((j >> s) << (s + 1)) + pos;
      int i1 = i0 + half;
      float2 w = tw[pos << (9 - s)];
      float2 u = ag[i0], v = ag[i1];
      float tr = w.x * v.x - w.y * v.y;
      float ti = w.x * v.y + w.y * v.x;
      ag[i1] = make_float2(u.x - tr, u.y - ti);
      ag[i0] = make_float2(u.x + tr, u.y + ti);
    }
    __syncthreads();
  }
  float* yb = y + (size_t)b * NT * NK + k0;
  const float sc = 1.0f / 1024.0f;
  for (int idx = tid; idx < 8192; idx += 512) {
    int t = idx >> 3, kk = idx & 7;
    yb[(size_t)t * NK + kk] += a[kk * 1024 + t].x * sc;
  }
}

// ---------------- generic row-block linear layer ----------------
// C[M x N] = act(A[M x K] @ W[K x N] + bias). One workgroup = 32 rows.
// MODE 0: plain store, 1: bias + leaky-relu(0.01), 2: bias only.
template <int K, int N, int MODE>
__global__ __launch_bounds__(256) void lin_kernel(const float* __restrict__ A,
                                                  const float* __restrict__ W,
                                                  const float* __restrict__ bias,
                                                  float* __restrict__ C) {
  constexpr int GR = 256 / N;     // row groups per block
  constexpr int RPT = 32 / GR;    // rows per thread
  __shared__ __align__(16) float as[32 * K];
  const int tid = threadIdx.x;
  const int row0 = blockIdx.x * 32;
  const int n = tid % N;
  const int rs = tid / N;
  const float4* A4 = (const float4*)(A + (size_t)row0 * K);
  float4* as4 = (float4*)as;
  for (int q = tid; q < 32 * K / 4; q += 256) as4[q] = A4[q];
  __syncthreads();
  float acc[RPT];
#pragma unroll
  for (int r = 0; r < RPT; ++r) acc[r] = 0.0f;
  for (int i0 = 0; i0 < K; i0 += 4) {
    float w0 = W[(size_t)(i0 + 0) * N + n];
    float w1 = W[(size_t)(i0 + 1) * N + n];
    float w2 = W[(size_t)(i0 + 2) * N + n];
    float w3 = W[(size_t)(i0 + 3) * N + n];
#pragma unroll
    for (int r = 0; r < RPT; ++r) {
      float4 xa = as4[(rs * RPT + r) * (K / 4) + (i0 >> 2)];
      acc[r] = fmaf(xa.x, w0, acc[r]);
      acc[r] = fmaf(xa.y, w1, acc[r]);
      acc[r] = fmaf(xa.z, w2, acc[r]);
      acc[r] = fmaf(xa.w, w3, acc[r]);
    }
  }
#pragma unroll
  for (int r = 0; r < RPT; ++r) {
    float v = acc[r];
    if (MODE >= 1) v += bias[n];
    if (MODE == 1) v = (v > 0.0f) ? v : 0.01f * v;
    C[(size_t)(row0 + rs * RPT + r) * N + n] = v;
  }
}

extern "C" void kernel_launch(void* const* d_in, const int* in_sizes, int n_in,
                              void* d_out, int out_size, void* d_ws, size_t ws_size,
                              hipStream_t stream) {
  const float* x     = (const float*)d_in[0];
  const float* W_re  = (const float*)d_in[1];
  const float* W_im  = (const float*)d_in[2];
  const float* B_re  = (const float*)d_in[3];
  const float* B_im  = (const float*)d_in[4];
  const float* W_rc  = (const float*)d_in[5];
  const float* fc1_w = (const float*)d_in[6];
  const float* fc1_b = (const float*)d_in[7];
  const float* fc2_w = (const float*)d_in[8];
  const float* fc2_b = (const float*)d_in[9];
  float* out = (float*)d_out;

  // Workspace layout. y first (33.6MB), then Xc (8.4MB), Fc (16.8MB).
  // h reuses Xc+Fc region (33.6MB) after they are dead. Total 67.2 MB.
  const size_t SZ_X = (size_t)NB * NF * ND;  // 2,101,248
  const size_t SZ_F = (size_t)NB * NF * NK;  // 4,202,496
  const size_t SZ_Y = (size_t)NB * NT * NK;  // 8,388,608
  float* y = (float*)d_ws;
  unsigned* Xc = (unsigned*)(y + SZ_Y);
  unsigned* Fc = Xc + SZ_X;
  float* h = (float*)Xc;   // reused after irfft

  // 1) rfft of x along time (bf16-packed output)
  rfft_kernel<<<dim3(NB * 16), dim3(512), 0, stream>>>(x, Xc);
  // 2) per-frequency complex MLP + split-ReLU (bf16 MFMA)
  freq_mfma_kernel<<<dim3(NF), dim3(512), 0, stream>>>(Xc, W_re, W_im, B_re, B_im, Fc);
  // 3) residual projection: y = x @ W_rc
  lin_kernel<ND, NK, 0><<<dim3((NB * NT) / 32), dim3(256), 0, stream>>>(x, W_rc, nullptr, y);
  // 4) irfft, accumulate into y
  irfft_kernel<<<dim3(NB * 32), dim3(512), 0, stream>>>(Fc, y);
  // 5) fc1 + leaky relu
  lin_kernel<NK, NK, 1><<<dim3((NB * NT) / 32), dim3(256), 0, stream>>>(y, fc1_w, fc1_b, h);
  // 6) fc2 + bias -> out
  lin_kernel<NK, NO, 2><<<dim3((NB * NT) / 32), dim3(256), 0, stream>>>(h, fc2_w, fc2_b, out);
}

// Round 3
// 204.192 us; speedup vs baseline: 2.2046x; 1.6902x over previous
//
#include <hip/hip_runtime.h>
#include <math.h>

// Sizes
#define NB 32
#define NT 1024
#define ND 128     // D_IN
#define NK 256     // D_HID
#define NO 128     // D_OUT
#define NF 513     // NT/2 + 1

typedef __attribute__((ext_vector_type(8))) short bf16x8;
typedef __attribute__((ext_vector_type(4))) float f32x4;

__device__ __forceinline__ unsigned brev10(unsigned j) { return __brev(j) >> 22; }

__device__ __forceinline__ unsigned short f2bf(float f) {
  union { float f; unsigned u; } v; v.f = f;
  return (unsigned short)((v.u + 0x7fffu + ((v.u >> 16) & 1u)) >> 16);
}
__device__ __forceinline__ float bf2f(unsigned u) {
  union { unsigned u; float f; } v; v.u = u << 16;
  return v.f;
}
__device__ __forceinline__ unsigned packbf(float re, float im) {
  return (unsigned)f2bf(re) | ((unsigned)f2bf(im) << 16);
}

// ---------------- forward rfft along time axis ----------------
__global__ __launch_bounds__(512) void rfft_kernel(const float* __restrict__ x,
                                                   unsigned* __restrict__ Xc) {
  __shared__ float2 a[8 * 1024];   // 64 KB
  __shared__ float2 tw[512];       // 4 KB
  const int tid = threadIdx.x;
  const int b = blockIdx.x >> 4;
  const int d0 = (blockIdx.x & 15) << 3;
  {
    float s, c;
    sincosf(6.283185307179586f * (float)tid / 1024.0f, &s, &c);
    if (tid < 512) tw[tid] = make_float2(c, -s);   // exp(-2*pi*i*k/N)
  }
  const float* xb = x + (size_t)b * NT * ND + d0;
  for (int idx = tid; idx < 8192; idx += 512) {
    int t = idx >> 3, dd = idx & 7;
    a[dd * 1024 + t] = make_float2(xb[t * ND + dd], 0.0f);
  }
  __syncthreads();
  const int g = tid >> 6, l = tid & 63;
  float2* ag = a + g * 1024;
  for (int j = l; j < 1024; j += 64) {
    int r = (int)brev10((unsigned)j);
    if (j < r) { float2 t0 = ag[j]; ag[j] = ag[r]; ag[r] = t0; }
  }
  __syncthreads();
  for (int s = 0; s < 10; ++s) {
    const int half = 1 << s;
    for (int j = l; j < 512; j += 64) {
      int pos = j & (half - 1);
      int i0 = ((j >> s) << (s + 1)) + pos;
      int i1 = i0 + half;
      float2 w = tw[pos << (9 - s)];
      float2 u = ag[i0], v = ag[i1];
      float tr = w.x * v.x - w.y * v.y;
      float ti = w.x * v.y + w.y * v.x;
      ag[i1] = make_float2(u.x - tr, u.y - ti);
      ag[i0] = make_float2(u.x + tr, u.y + ti);
    }
    __syncthreads();
  }
  unsigned* Xb = Xc + (size_t)b * NF * ND + d0;
  for (int idx = tid; idx < NF * 8; idx += 512) {
    int f = idx >> 3, dd = idx & 7;
    float2 v = a[dd * 1024 + f];
    Xb[(size_t)f * ND + dd] = packbf(v.x, v.y);
  }
}

// ---------------- per-frequency complex MLP (bf16 MFMA) ----------------
__global__ __launch_bounds__(512) void freq_mfma_kernel(
    const unsigned* __restrict__ Xc, const float* __restrict__ Wre,
    const float* __restrict__ Wim, const float* __restrict__ Bre,
    const float* __restrict__ Bim, unsigned* __restrict__ Fc) {
  __shared__ unsigned short Xr_l[NB * ND], Xi_l[NB * ND], Xn_l[NB * ND]; // 24 KB
  const int tid = threadIdx.x;
  const int f = blockIdx.x;
#pragma unroll
  for (int it = 0; it < 8; ++it) {
    int idx = it * 512 + tid;
    int d = idx & 127, b = idx >> 7;
    unsigned p = Xc[((size_t)b * NF + f) * ND + d];
    int off = b * 128 + ((((d >> 3) ^ (b & 15))) << 3) + (d & 7);
    unsigned short re = (unsigned short)(p & 0xffff);
    unsigned short im = (unsigned short)(p >> 16);
    Xr_l[off] = re; Xi_l[off] = im; Xn_l[off] = im ^ 0x8000;
  }
  __syncthreads();
  const int wv = tid >> 6, l = tid & 63;
  const int lr = l & 15, lg = l >> 4;
  const int n0 = wv * 32;
  f32x4 aR[2][2], aI[2][2];
#pragma unroll
  for (int nt = 0; nt < 2; ++nt) {
    float br = Bre[(size_t)f * NK + n0 + nt * 16 + lr];
    float bi = Bim[(size_t)f * NK + n0 + nt * 16 + lr];
#pragma unroll
    for (int m = 0; m < 2; ++m) {
      aR[m][nt] = (f32x4){br, br, br, br};
      aI[m][nt] = (f32x4){bi, bi, bi, bi};
    }
  }
#pragma unroll 2
  for (int ks = 0; ks < 4; ++ks) {
    bf16x8 xr[2], xi[2], xn[2];
#pragma unroll
    for (int m = 0; m < 2; ++m) {
      int row = m * 16 + lr;
      int off = row * 128 + (((ks * 4 + lg) ^ lr) << 3);
      xr[m] = *(const bf16x8*)&Xr_l[off];
      xi[m] = *(const bf16x8*)&Xi_l[off];
      xn[m] = *(const bf16x8*)&Xn_l[off];
    }
#pragma unroll
    for (int nt = 0; nt < 2; ++nt) {
      int col = n0 + nt * 16 + lr;
      const float* wr = Wre + ((size_t)f * ND + ks * 32 + lg * 8) * NK + col;
      const float* wi = Wim + ((size_t)f * ND + ks * 32 + lg * 8) * NK + col;
      bf16x8 bR, bI;
#pragma unroll
      for (int j = 0; j < 8; ++j) {
        bR[j] = (short)f2bf(wr[(size_t)j * NK]);
        bI[j] = (short)f2bf(wi[(size_t)j * NK]);
      }
#pragma unroll
      for (int m = 0; m < 2; ++m) {
        aR[m][nt] = __builtin_amdgcn_mfma_f32_16x16x32_bf16(xr[m], bR, aR[m][nt], 0, 0, 0);
        aR[m][nt] = __builtin_amdgcn_mfma_f32_16x16x32_bf16(xn[m], bI, aR[m][nt], 0, 0, 0);
        aI[m][nt] = __builtin_amdgcn_mfma_f32_16x16x32_bf16(xr[m], bI, aI[m][nt], 0, 0, 0);
        aI[m][nt] = __builtin_amdgcn_mfma_f32_16x16x32_bf16(xi[m], bR, aI[m][nt], 0, 0, 0);
      }
    }
  }
#pragma unroll
  for (int m = 0; m < 2; ++m)
#pragma unroll
    for (int nt = 0; nt < 2; ++nt)
#pragma unroll
      for (int r = 0; r < 4; ++r) {
        int brow = m * 16 + lg * 4 + r;
        int col = n0 + nt * 16 + lr;
        float vR = fmaxf(aR[m][nt][r], 0.0f);
        float vI = fmaxf(aI[m][nt][r], 0.0f);
        Fc[((size_t)brow * NF + f) * NK + col] = packbf(vR, vI);
      }
}

// ---------------- inverse rfft -> bf16 yf ----------------
__global__ __launch_bounds__(512) void irfft_kernel(const unsigned* __restrict__ Fc,
                                                    unsigned short* __restrict__ yf) {
  __shared__ float2 a[8 * 1024];
  __shared__ float2 tw[512];
  const int tid = threadIdx.x;
  const int b = blockIdx.x >> 5;
  const int k0 = (blockIdx.x & 31) << 3;
  {
    float s, c;
    sincosf(6.283185307179586f * (float)tid / 1024.0f, &s, &c);
    if (tid < 512) tw[tid] = make_float2(c, s);    // exp(+2*pi*i*k/N)
  }
  for (int idx = tid; idx < NF * 8; idx += 512) {
    int f = idx >> 3, kk = idx & 7;
    unsigned p = Fc[((size_t)b * NF + f) * NK + k0 + kk];
    a[kk * 1024 + f] = make_float2(bf2f(p & 0xffff), bf2f(p >> 16));
  }
  __syncthreads();
  for (int idx = tid; idx < 511 * 8; idx += 512) {
    int f = 513 + (idx >> 3), kk = idx & 7;
    float2 v = a[kk * 1024 + (1024 - f)];
    a[kk * 1024 + f] = make_float2(v.x, -v.y);
  }
  __syncthreads();
  const int g = tid >> 6, l = tid & 63;
  float2* ag = a + g * 1024;
  for (int j = l; j < 1024; j += 64) {
    int r = (int)brev10((unsigned)j);
    if (j < r) { float2 t0 = ag[j]; ag[j] = ag[r]; ag[r] = t0; }
  }
  __syncthreads();
  for (int s = 0; s < 10; ++s) {
    const int half = 1 << s;
    for (int j = l; j < 512; j += 64) {
      int pos = j & (half - 1);
      int i0 = ((j >> s) << (s + 1)) + pos;
      int i1 = i0 + half;
      float2 w = tw[pos << (9 - s)];
      float2 u = ag[i0], v = ag[i1];
      float tr = w.x * v.x - w.y * v.y;
      float ti = w.x * v.y + w.y * v.x;
      ag[i1] = make_float2(u.x - tr, u.y - ti);
      ag[i0] = make_float2(u.x + tr, u.y + ti);
    }
    __syncthreads();
  }
  unsigned short* yb = yf + (size_t)b * NT * NK + k0;
  const float sc = 1.0f / 1024.0f;
  for (int idx = tid; idx < 8192; idx += 512) {
    int t = idx >> 3, kk = idx & 7;
    yb[(size_t)t * NK + kk] = f2bf(a[kk * 1024 + t].x * sc);
  }
}

// ---------------- weight convert + transpose to bf16 ----------------
// Wt layout: [0:32768) Wrc_t[256][128]; [32768:98304) W1_t[256][256];
// [98304:131072) W2_t[128][256].   (Wt_t[n][k] = W[k][n])
__global__ __launch_bounds__(256) void wconv_kernel(const float* __restrict__ Wrc,
                                                    const float* __restrict__ W1,
                                                    const float* __restrict__ W2,
                                                    unsigned short* __restrict__ Wt) {
  int i = blockIdx.x * 256 + threadIdx.x;
  if (i < 32768) {
    int k = i >> 8, n = i & 255;
    Wt[n * 128 + k] = f2bf(Wrc[i]);
  } else if (i < 98304) {
    int j = i - 32768; int k = j >> 8, n = j & 255;
    Wt[32768 + n * 256 + k] = f2bf(W1[j]);
  } else if (i < 131072) {
    int j = i - 98304; int k = j >> 7, n = j & 127;
    Wt[98304 + n * 256 + k] = f2bf(W2[j]);
  }
}

// ---------------- fused MLP tail ----------------
// Per 64-row block: P = x@W_rc ; y = P + yf (LDS bf16) ; h = leaky(y@W1+b1)
// (LDS bf16) ; out = h@W2 + b2. 8 waves: mw = wv>>1 (16-row slice),
// nw = wv&1 (128-col slice of NK).
__global__ __launch_bounds__(512) void mlp_fused_kernel(
    const float* __restrict__ x, const unsigned short* __restrict__ yf,
    const unsigned short* __restrict__ Wt, const float* __restrict__ b1,
    const float* __restrict__ b2, float* __restrict__ out) {
  __shared__ unsigned short y_l[64 * 256];  // 32 KB
  __shared__ unsigned short h_l[64 * 256];  // 32 KB
  const int tid = threadIdx.x;
  const int wv = tid >> 6, l = tid & 63;
  const int lr = l & 15, lg = l >> 4;
  const int mw = wv >> 1, nw = wv & 1;
  const int row0 = blockIdx.x * 64;
  const unsigned short* Wrc_t = Wt;           // [256][128]
  const unsigned short* W1_t  = Wt + 32768;   // [256][256]
  const unsigned short* W2_t  = Wt + 98304;   // [128][256]

  const int arow = mw * 16 + lr;              // A row (local)

  // ---- GEMM1: P = x @ W_rc (K=128) ----
  f32x4 acc[8];
#pragma unroll
  for (int nt = 0; nt < 8; ++nt) acc[nt] = (f32x4){0.f, 0.f, 0.f, 0.f};
#pragma unroll
  for (int ks = 0; ks < 4; ++ks) {
    const float4* xp = (const float4*)(x + (size_t)(row0 + arow) * ND + ks * 32 + lg * 8);
    float4 a0 = xp[0], a1 = xp[1];
    bf16x8 af;
    af[0] = (short)f2bf(a0.x); af[1] = (short)f2bf(a0.y);
    af[2] = (short)f2bf(a0.z); af[3] = (short)f2bf(a0.w);
    af[4] = (short)f2bf(a1.x); af[5] = (short)f2bf(a1.y);
    af[6] = (short)f2bf(a1.z); af[7] = (short)f2bf(a1.w);
#pragma unroll
    for (int nt = 0; nt < 8; ++nt) {
      int col = nw * 128 + nt * 16 + lr;
      bf16x8 bf = *(const bf16x8*)&Wrc_t[col * 128 + ks * 32 + lg * 8];
      acc[nt] = __builtin_amdgcn_mfma_f32_16x16x32_bf16(af, bf, acc[nt], 0, 0, 0);
    }
  }
  // epilogue: + residual yf -> y_l (swizzled bf16)
#pragma unroll
  for (int nt = 0; nt < 8; ++nt)
#pragma unroll
    for (int r = 0; r < 4; ++r) {
      int rl = mw * 16 + lg * 4 + r;
      int col = nw * 128 + nt * 16 + lr;
      float v = acc[nt][r] + bf2f(yf[(size_t)(row0 + rl) * NK + col]);
      int blk = (col >> 3) ^ (rl & 31);
      y_l[rl * 256 + blk * 8 + (col & 7)] = f2bf(v);
    }
  __syncthreads();

  // ---- GEMM2: h = leaky(y @ W1 + b1) (K=256) ----
#pragma unroll
  for (int nt = 0; nt < 8; ++nt) {
    float bv = b1[nw * 128 + nt * 16 + lr];
    acc[nt] = (f32x4){bv, bv, bv, bv};
  }
#pragma unroll
  for (int ks = 0; ks < 8; ++ks) {
    int blk = (ks * 4 + lg) ^ (arow & 31);
    bf16x8 af = *(const bf16x8*)&y_l[arow * 256 + blk * 8];
#pragma unroll
    for (int nt = 0; nt < 8; ++nt) {
      int col = nw * 128 + nt * 16 + lr;
      bf16x8 bf = *(const bf16x8*)&W1_t[col * 256 + ks * 32 + lg * 8];
      acc[nt] = __builtin_amdgcn_mfma_f32_16x16x32_bf16(af, bf, acc[nt], 0, 0, 0);
    }
  }
#pragma unroll
  for (int nt = 0; nt < 8; ++nt)
#pragma unroll
    for (int r = 0; r < 4; ++r) {
      int rl = mw * 16 + lg * 4 + r;
      int col = nw * 128 + nt * 16 + lr;
      float v = acc[nt][r];
      v = (v > 0.0f) ? v : 0.01f * v;
      int blk = (col >> 3) ^ (rl & 31);
      h_l[rl * 256 + blk * 8 + (col & 7)] = f2bf(v);
    }
  __syncthreads();

  // ---- GEMM3: out = h @ W2 + b2 (K=256, N=128) ----
  f32x4 acc3[4];
#pragma unroll
  for (int nt = 0; nt < 4; ++nt) {
    float bv = b2[nw * 64 + nt * 16 + lr];
    acc3[nt] = (f32x4){bv, bv, bv, bv};
  }
#pragma unroll
  for (int ks = 0; ks < 8; ++ks) {
    int blk = (ks * 4 + lg) ^ (arow & 31);
    bf16x8 af = *(const bf16x8*)&h_l[arow * 256 + blk * 8];
#pragma unroll
    for (int nt = 0; nt < 4; ++nt) {
      int col = nw * 64 + nt * 16 + lr;
      bf16x8 bf = *(const bf16x8*)&W2_t[col * 256 + ks * 32 + lg * 8];
      acc3[nt] = __builtin_amdgcn_mfma_f32_16x16x32_bf16(af, bf, acc3[nt], 0, 0, 0);
    }
  }
#pragma unroll
  for (int nt = 0; nt < 4; ++nt)
#pragma unroll
    for (int r = 0; r < 4; ++r) {
      int rl = mw * 16 + lg * 4 + r;
      int col = nw * 64 + nt * 16 + lr;
      out[(size_t)(row0 + rl) * NO + col] = acc3[nt][r];
    }
}

extern "C" void kernel_launch(void* const* d_in, const int* in_sizes, int n_in,
                              void* d_out, int out_size, void* d_ws, size_t ws_size,
                              hipStream_t stream) {
  const float* x     = (const float*)d_in[0];
  const float* W_re  = (const float*)d_in[1];
  const float* W_im  = (const float*)d_in[2];
  const float* B_re  = (const float*)d_in[3];
  const float* B_im  = (const float*)d_in[4];
  const float* W_rc  = (const float*)d_in[5];
  const float* fc1_w = (const float*)d_in[6];
  const float* fc1_b = (const float*)d_in[7];
  const float* fc2_w = (const float*)d_in[8];
  const float* fc2_b = (const float*)d_in[9];
  float* out = (float*)d_out;

  // Workspace: Xc 8.4MB | Fc 16.8MB | yf 16.8MB | Wt 0.26MB  (~42.3MB)
  const size_t SZ_X = (size_t)NB * NF * ND;  // 2,101,248
  const size_t SZ_F = (size_t)NB * NF * NK;  // 4,202,496
  const size_t SZ_Y = (size_t)NB * NT * NK;  // 8,388,608
  unsigned* Xc = (unsigned*)d_ws;
  unsigned* Fc = Xc + SZ_X;
  unsigned short* yf = (unsigned short*)(Fc + SZ_F);
  unsigned short* Wt = yf + SZ_Y;

  // 0) convert small weights to transposed bf16
  wconv_kernel<<<dim3(512), dim3(256), 0, stream>>>(W_rc, fc1_w, fc2_w, Wt);
  // 1) rfft of x along time (bf16-packed output)
  rfft_kernel<<<dim3(NB * 16), dim3(512), 0, stream>>>(x, Xc);
  // 2) per-frequency complex MLP + split-ReLU (bf16 MFMA)
  freq_mfma_kernel<<<dim3(NF), dim3(512), 0, stream>>>(Xc, W_re, W_im, B_re, B_im, Fc);
  // 3) irfft -> bf16 yf
  irfft_kernel<<<dim3(NB * 32), dim3(512), 0, stream>>>(Fc, yf);
  // 4) fused residual-proj + fc1 + fc2
  mlp_fused_kernel<<<dim3((NB * NT) / 64), dim3(512), 0, stream>>>(x, yf, Wt, fc1_b, fc2_b, out);
}

// Round 4
// 101.529 us; speedup vs baseline: 4.4337x; 2.0112x over previous
//
#include <hip/hip_runtime.h>
#include <math.h>

// Sizes
#define NB 32
#define NT 1024
#define ND 128     // D_IN
#define NK 256     // D_HID
#define NO 128     // D_OUT
#define NF 513     // NT/2 + 1

#define PAD(e) ((e) + ((e) >> 4))

typedef __attribute__((ext_vector_type(8))) short bf16x8;
typedef __attribute__((ext_vector_type(4))) float f32x4;

__device__ __forceinline__ unsigned short f2bf(float f) {
  union { float f; unsigned u; } v; v.f = f;
  return (unsigned short)((v.u + 0x7fffu + ((v.u >> 16) & 1u)) >> 16);
}
__device__ __forceinline__ float bf2f(unsigned u) {
  union { unsigned u; float f; } v; v.u = u << 16;
  return v.f;
}
__device__ __forceinline__ unsigned packbf(float re, float im) {
  return (unsigned)f2bf(re) | ((unsigned)f2bf(im) << 16);
}
// base-4 digit reversal of 10-bit index
__device__ __forceinline__ unsigned digrev4(unsigned j) {
  unsigned r = __brev(j) >> 22;
  return ((r & 0x2AAu) >> 1) | ((r & 0x155u) << 1);
}

// In-place 1024-pt radix-4 FFT, one wave per FFT, SoA re/im with PAD.
// tw tables hold (cos, ±sin): -sin for forward, +sin for inverse.
template <bool INV>
__device__ void fft1024_r4(float* __restrict__ ar, float* __restrict__ ai,
                           const float* __restrict__ twc,
                           const float* __restrict__ tws, int l) {
  for (int j = l; j < 1024; j += 64) {
    int r = (int)digrev4((unsigned)j);
    if (j < r) {
      int pj = PAD(j), pr = PAD(r);
      float t0 = ar[pj], t1 = ai[pj];
      ar[pj] = ar[pr]; ai[pj] = ai[pr];
      ar[pr] = t0; ai[pr] = t1;
    }
  }
#pragma unroll
  for (int s = 0; s < 5; ++s) {
    const int sh = 2 * s;
    const int q = 1 << sh;
#pragma unroll
    for (int it = 0; it < 4; ++it) {
      int m = it * 64 + l;
      int r = m & (q - 1);
      int i0 = ((m >> sh) << (sh + 2)) + r;
      int p0 = PAD(i0), p1 = PAD(i0 + q), p2 = PAD(i0 + 2 * q), p3 = PAD(i0 + 3 * q);
      float x0r = ar[p0], x0i = ai[p0];
      float x1r = ar[p1], x1i = ai[p1];
      float x2r = ar[p2], x2i = ai[p2];
      float x3r = ar[p3], x3i = ai[p3];
      float t1r, t1i, t2r, t2i, t3r, t3i;
      if (s == 0) {
        t1r = x1r; t1i = x1i; t2r = x2r; t2i = x2i; t3r = x3r; t3i = x3i;
      } else {
        int e = r << (8 - sh);
        float c1 = twc[e], s1 = tws[e];
        float c2 = c1 * c1 - s1 * s1, s2 = 2.0f * c1 * s1;
        float c3 = c1 * c2 - s1 * s2, s3 = c1 * s2 + s1 * c2;
        t1r = x1r * c1 - x1i * s1; t1i = x1r * s1 + x1i * c1;
        t2r = x2r * c2 - x2i * s2; t2i = x2r * s2 + x2i * c2;
        t3r = x3r * c3 - x3i * s3; t3i = x3r * s3 + x3i * c3;
      }
      float u0r = x0r + t2r, u0i = x0i + t2i;
      float u1r = x0r - t2r, u1i = x0i - t2i;
      float u2r = t1r + t3r, u2i = t1i + t3i;
      float u3r = t1r - t3r, u3i = t1i - t3i;
      ar[p0] = u0r + u2r; ai[p0] = u0i + u2i;
      ar[p2] = u0r - u2r; ai[p2] = u0i - u2i;
      if (INV) {
        ar[p1] = u1r - u3i; ai[p1] = u1i + u3r;
        ar[p3] = u1r + u3i; ai[p3] = u1i - u3r;
      } else {
        ar[p1] = u1r + u3i; ai[p1] = u1i - u3r;
        ar[p3] = u1r - u3i; ai[p3] = u1i + u3r;
      }
    }
  }
}

// ---------------- forward rfft: 16 channels/block, 8 packed FFTs ----------------
__global__ __launch_bounds__(512, 4) void rfft_kernel(const float* __restrict__ x,
                                                      unsigned* __restrict__ Xc) {
  __shared__ float ar[8 * 1088], ai_[8 * 1088];  // 68 KB
  __shared__ float twc[768], tws[768];           // 6 KB
  const int tid = threadIdx.x;
  const int b = blockIdx.x >> 3;
  const int c0 = (blockIdx.x & 7) << 4;
  for (int k = tid; k < 768; k += 512) {
    float s, c;
    sincosf(6.283185307179586f * (float)k / 1024.0f, &s, &c);
    twc[k] = c; tws[k] = -s;
  }
  const float* xb = x + (size_t)b * NT * ND + c0;
  for (int idx = tid; idx < 8192; idx += 512) {
    int t = idx >> 3, g = idx & 7;
    float2 v = *(const float2*)(xb + (size_t)t * ND + 2 * g);
    int p = g * 1088 + PAD(t);
    ar[p] = v.x; ai_[p] = v.y;
  }
  __syncthreads();
  const int g = tid >> 6, l = tid & 63;
  fft1024_r4<false>(ar + g * 1088, ai_ + g * 1088, twc, tws, l);
  __syncthreads();
  // hermitian separation: ch c0+2g = even, c0+2g+1 = odd
  unsigned* Xb = Xc + (size_t)b * NF * ND + c0;
  for (int idx = tid; idx < NF * 8; idx += 512) {
    int f = idx >> 3, gg = idx & 7;
    int mr = (1024 - f) & 1023;
    int pf = gg * 1088 + PAD(f), pm = gg * 1088 + PAD(mr);
    float x1 = ar[pf], y1 = ai_[pf];
    float xr = ar[pm], yr = ai_[pm];
    unsigned e0 = packbf(0.5f * (x1 + xr), 0.5f * (y1 - yr));
    unsigned e1 = packbf(0.5f * (y1 + yr), 0.5f * (xr - x1));
    *(uint2*)(Xb + (size_t)f * ND + 2 * gg) = make_uint2(e0, e1);
  }
}

// ---------------- per-frequency complex MLP (bf16 MFMA) ----------------
// Grid NF*2: block = (f, 128-col half). 8 waves, wave = 16 cols.
__global__ __launch_bounds__(512, 4) void freq_mfma_kernel(
    const unsigned* __restrict__ Xc, const float* __restrict__ Wre,
    const float* __restrict__ Wim, const float* __restrict__ Bre,
    const float* __restrict__ Bim, unsigned* __restrict__ Fc) {
  __shared__ unsigned short Xr_l[NB * ND], Xi_l[NB * ND], Xn_l[NB * ND]; // 24 KB
  const int tid = threadIdx.x;
  const int f = blockIdx.x >> 1;
  const int nh = blockIdx.x & 1;
#pragma unroll
  for (int it = 0; it < 8; ++it) {
    int idx = it * 512 + tid;
    int d = idx & 127, b = idx >> 7;
    unsigned p = Xc[((size_t)b * NF + f) * ND + d];
    int off = b * 128 + ((((d >> 3) ^ (b & 15))) << 3) + (d & 7);
    unsigned short re = (unsigned short)(p & 0xffff);
    unsigned short im = (unsigned short)(p >> 16);
    Xr_l[off] = re; Xi_l[off] = im; Xn_l[off] = im ^ 0x8000;
  }
  __syncthreads();
  const int wv = tid >> 6, l = tid & 63;
  const int lr = l & 15, lg = l >> 4;
  const int n0 = nh * 128 + wv * 16;
  f32x4 aR[2], aI[2];
  {
    float br = Bre[(size_t)f * NK + n0 + lr];
    float bi = Bim[(size_t)f * NK + n0 + lr];
    aR[0] = (f32x4){br, br, br, br}; aR[1] = aR[0];
    aI[0] = (f32x4){bi, bi, bi, bi}; aI[1] = aI[0];
  }
#pragma unroll
  for (int ks = 0; ks < 4; ++ks) {
    const float* wr = Wre + ((size_t)f * ND + ks * 32 + lg * 8) * NK + n0 + lr;
    const float* wi = Wim + ((size_t)f * ND + ks * 32 + lg * 8) * NK + n0 + lr;
    float fr[8], fi[8];
#pragma unroll
    for (int j = 0; j < 8; ++j) { fr[j] = wr[(size_t)j * NK]; fi[j] = wi[(size_t)j * NK]; }
    bf16x8 xr[2], xi[2], xn[2];
#pragma unroll
    for (int m = 0; m < 2; ++m) {
      int row = m * 16 + lr;
      int off = row * 128 + (((ks * 4 + lg) ^ lr) << 3);
      xr[m] = *(const bf16x8*)&Xr_l[off];
      xi[m] = *(const bf16x8*)&Xi_l[off];
      xn[m] = *(const bf16x8*)&Xn_l[off];
    }
    bf16x8 bR, bI;
#pragma unroll
    for (int j = 0; j < 8; ++j) { bR[j] = (short)f2bf(fr[j]); bI[j] = (short)f2bf(fi[j]); }
#pragma unroll
    for (int m = 0; m < 2; ++m) {
      aR[m] = __builtin_amdgcn_mfma_f32_16x16x32_bf16(xr[m], bR, aR[m], 0, 0, 0);
      aR[m] = __builtin_amdgcn_mfma_f32_16x16x32_bf16(xn[m], bI, aR[m], 0, 0, 0);
      aI[m] = __builtin_amdgcn_mfma_f32_16x16x32_bf16(xr[m], bI, aI[m], 0, 0, 0);
      aI[m] = __builtin_amdgcn_mfma_f32_16x16x32_bf16(xi[m], bR, aI[m], 0, 0, 0);
    }
  }
#pragma unroll
  for (int m = 0; m < 2; ++m)
#pragma unroll
    for (int r = 0; r < 4; ++r) {
      int brow = m * 16 + lg * 4 + r;
      float vR = fmaxf(aR[m][r], 0.0f);
      float vI = fmaxf(aI[m][r], 0.0f);
      Fc[((size_t)brow * NF + f) * NK + n0 + lr] = packbf(vR, vI);
    }
}

// ---------------- inverse rfft: 16 channels/block, 8 packed inverse FFTs ----------------
__global__ __launch_bounds__(512, 4) void irfft_kernel(const unsigned* __restrict__ Fc,
                                                       unsigned short* __restrict__ yf) {
  __shared__ float ar[8 * 1088], ai_[8 * 1088];
  __shared__ float twc[768], tws[768];
  const int tid = threadIdx.x;
  const int b = blockIdx.x >> 4;
  const int k0 = (blockIdx.x & 15) << 4;
  for (int k = tid; k < 768; k += 512) {
    float s, c;
    sincosf(6.283185307179586f * (float)k / 1024.0f, &s, &c);
    twc[k] = c; tws[k] = s;   // inverse: conjugated twiddles
  }
  // build Z[f] = Fa[f] + i*Fb[f] with hermitian extension
  for (int idx = tid; idx < 8192; idx += 512) {
    int f = idx >> 3, g = idx & 7;
    int src = (f <= 512) ? f : 1024 - f;
    uint2 u = *(const uint2*)(Fc + ((size_t)b * NF + src) * NK + k0 + 2 * g);
    float arr = bf2f(u.x & 0xffff), ari = bf2f(u.x >> 16);
    float brr = bf2f(u.y & 0xffff), bri = bf2f(u.y >> 16);
    float zr, zi;
    if (f <= 512) { zr = arr - bri; zi = ari + brr; }
    else          { zr = arr + bri; zi = brr - ari; }
    int p = g * 1088 + PAD(f);
    ar[p] = zr; ai_[p] = zi;
  }
  __syncthreads();
  const int g = tid >> 6, l = tid & 63;
  fft1024_r4<true>(ar + g * 1088, ai_ + g * 1088, twc, tws, l);
  __syncthreads();
  const float sc = 1.0f / 1024.0f;
  unsigned* yb = (unsigned*)(yf + (size_t)b * NT * NK + k0);
  for (int idx = tid; idx < 8192; idx += 512) {
    int t = idx >> 3, gg = idx & 7;
    int p = gg * 1088 + PAD(t);
    yb[(size_t)t * (NK / 2) + gg] = packbf(ar[p] * sc, ai_[p] * sc);
  }
}

// ---------------- weight convert + transpose to bf16 ----------------
// Wt: [0:32768) Wrc_t[256][128]; [32768:98304) W1_t[256][256]; [98304:131072) W2_t[128][256]
__global__ __launch_bounds__(256) void wconv_kernel(const float* __restrict__ Wrc,
                                                    const float* __restrict__ W1,
                                                    const float* __restrict__ W2,
                                                    unsigned short* __restrict__ Wt) {
  int i = blockIdx.x * 256 + threadIdx.x;
  if (i < 32768) {
    int k = i >> 8, n = i & 255;
    Wt[n * 128 + k] = f2bf(Wrc[i]);
  } else if (i < 98304) {
    int j = i - 32768; int k = j >> 8, n = j & 255;
    Wt[32768 + n * 256 + k] = f2bf(W1[j]);
  } else if (i < 131072) {
    int j = i - 98304; int k = j >> 7, n = j & 127;
    Wt[98304 + n * 256 + k] = f2bf(W2[j]);
  }
}

// ---------------- fused MLP tail ----------------
// Block = 64 rows. Wave = 64 rows x 32 cols (GEMM1/2), 64 x 16 (GEMM3).
__global__ __launch_bounds__(512, 4) void mlp_fused_kernel(
    const float* __restrict__ x, const unsigned short* __restrict__ yf,
    const unsigned short* __restrict__ Wt, const float* __restrict__ b1,
    const float* __restrict__ b2, float* __restrict__ out) {
  __shared__ unsigned short y_l[64 * 256];  // 32 KB
  __shared__ unsigned short u_l[64 * 256];  // 32 KB: x-tile (bf16), then h
  const int tid = threadIdx.x;
  const int wv = tid >> 6, l = tid & 63;
  const int lr = l & 15, lg = l >> 4;
  const int row0 = blockIdx.x * 64;
  const unsigned short* W1_t = Wt + 32768;
  const unsigned short* W2_t = Wt + 98304;

  // stage x -> u_l [64][128] bf16, 16B-block swizzle
#pragma unroll
  for (int it = 0; it < 4; ++it) {
    int idx = it * 512 + tid;
    int row = idx >> 5, c4 = idx & 31;
    float4 v = *(const float4*)(x + (size_t)(row0 + row) * ND + c4 * 4);
    int blk = (c4 >> 1) ^ (row & 15);
    unsigned short* p = &u_l[row * 128 + blk * 8 + (c4 & 1) * 4];
    p[0] = f2bf(v.x); p[1] = f2bf(v.y); p[2] = f2bf(v.z); p[3] = f2bf(v.w);
  }
  __syncthreads();

  // ---- GEMM1: P = x @ W_rc (K=128) ----
  f32x4 acc[4][2];
#pragma unroll
  for (int m = 0; m < 4; ++m)
#pragma unroll
    for (int nt = 0; nt < 2; ++nt) acc[m][nt] = (f32x4){0.f, 0.f, 0.f, 0.f};
#pragma unroll
  for (int ks = 0; ks < 4; ++ks) {
    bf16x8 bb[2];
#pragma unroll
    for (int nt = 0; nt < 2; ++nt) {
      int col = wv * 32 + nt * 16 + lr;
      bb[nt] = *(const bf16x8*)&Wt[col * 128 + ks * 32 + lg * 8];
    }
    bf16x8 aa[4];
#pragma unroll
    for (int m = 0; m < 4; ++m) {
      int row = m * 16 + lr;
      aa[m] = *(const bf16x8*)&u_l[row * 128 + (((ks * 4 + lg) ^ (row & 15)) << 3)];
    }
#pragma unroll
    for (int m = 0; m < 4; ++m)
#pragma unroll
      for (int nt = 0; nt < 2; ++nt)
        acc[m][nt] = __builtin_amdgcn_mfma_f32_16x16x32_bf16(aa[m], bb[nt], acc[m][nt], 0, 0, 0);
  }
  // epilogue: y = P + yf -> y_l (swizzled bf16)
#pragma unroll
  for (int m = 0; m < 4; ++m)
#pragma unroll
    for (int nt = 0; nt < 2; ++nt)
#pragma unroll
      for (int r = 0; r < 4; ++r) {
        int row = m * 16 + lg * 4 + r;
        int col = wv * 32 + nt * 16 + lr;
        float v = acc[m][nt][r] + bf2f(yf[(size_t)(row0 + row) * NK + col]);
        int blk = (col >> 3) ^ (row & 31);
        y_l[row * 256 + blk * 8 + (col & 7)] = f2bf(v);
      }
  __syncthreads();

  // ---- GEMM2: h = leaky(y @ W1 + b1) (K=256) ----
  f32x4 a2[4][2];
  {
    float bv0 = b1[wv * 32 + lr], bv1 = b1[wv * 32 + 16 + lr];
#pragma unroll
    for (int m = 0; m < 4; ++m) {
      a2[m][0] = (f32x4){bv0, bv0, bv0, bv0};
      a2[m][1] = (f32x4){bv1, bv1, bv1, bv1};
    }
  }
#pragma unroll
  for (int ks = 0; ks < 8; ++ks) {
    bf16x8 bb[2];
#pragma unroll
    for (int nt = 0; nt < 2; ++nt) {
      int col = wv * 32 + nt * 16 + lr;
      bb[nt] = *(const bf16x8*)&W1_t[col * 256 + ks * 32 + lg * 8];
    }
    bf16x8 aa[4];
#pragma unroll
    for (int m = 0; m < 4; ++m) {
      int row = m * 16 + lr;
      aa[m] = *(const bf16x8*)&y_l[row * 256 + (((ks * 4 + lg) ^ (row & 31)) << 3)];
    }
#pragma unroll
    for (int m = 0; m < 4; ++m)
#pragma unroll
      for (int nt = 0; nt < 2; ++nt)
        a2[m][nt] = __builtin_amdgcn_mfma_f32_16x16x32_bf16(aa[m], bb[nt], a2[m][nt], 0, 0, 0);
  }
#pragma unroll
  for (int m = 0; m < 4; ++m)
#pragma unroll
    for (int nt = 0; nt < 2; ++nt)
#pragma unroll
      for (int r = 0; r < 4; ++r) {
        int row = m * 16 + lg * 4 + r;
        int col = wv * 32 + nt * 16 + lr;
        float v = a2[m][nt][r];
        v = (v > 0.0f) ? v : 0.01f * v;
        int blk = (col >> 3) ^ (row & 31);
        u_l[row * 256 + blk * 8 + (col & 7)] = f2bf(v);
      }
  __syncthreads();

  // ---- GEMM3: out = h @ W2 + b2 (K=256, N=128) ----
  const int col3 = wv * 16 + lr;
  f32x4 a3[4];
  {
    float bv = b2[col3];
#pragma unroll
    for (int m = 0; m < 4; ++m) a3[m] = (f32x4){bv, bv, bv, bv};
  }
#pragma unroll
  for (int ks = 0; ks < 8; ++ks) {
    bf16x8 bb = *(const bf16x8*)&W2_t[col3 * 256 + ks * 32 + lg * 8];
    bf16x8 aa[4];
#pragma unroll
    for (int m = 0; m < 4; ++m) {
      int row = m * 16 + lr;
      aa[m] = *(const bf16x8*)&u_l[row * 256 + (((ks * 4 + lg) ^ (row & 31)) << 3)];
    }
#pragma unroll
    for (int m = 0; m < 4; ++m)
      a3[m] = __builtin_amdgcn_mfma_f32_16x16x32_bf16(aa[m], bb, a3[m], 0, 0, 0);
  }
#pragma unroll
  for (int m = 0; m < 4; ++m)
#pragma unroll
    for (int r = 0; r < 4; ++r) {
      int row = m * 16 + lg * 4 + r;
      out[(size_t)(row0 + row) * NO + col3] = a3[m][r];
    }
}

extern "C" void kernel_launch(void* const* d_in, const int* in_sizes, int n_in,
                              void* d_out, int out_size, void* d_ws, size_t ws_size,
                              hipStream_t stream) {
  const float* x     = (const float*)d_in[0];
  const float* W_re  = (const float*)d_in[1];
  const float* W_im  = (const float*)d_in[2];
  const float* B_re  = (const float*)d_in[3];
  const float* B_im  = (const float*)d_in[4];
  const float* W_rc  = (const float*)d_in[5];
  const float* fc1_w = (const float*)d_in[6];
  const float* fc1_b = (const float*)d_in[7];
  const float* fc2_w = (const float*)d_in[8];
  const float* fc2_b = (const float*)d_in[9];
  float* out = (float*)d_out;

  // Workspace: Xc 8.4MB | Fc 16.8MB | yf 16.8MB | Wt 0.26MB
  const size_t SZ_X = (size_t)NB * NF * ND;  // 2,101,248
  const size_t SZ_F = (size_t)NB * NF * NK;  // 4,202,496
  const size_t SZ_Y = (size_t)NB * NT * NK;  // 8,388,608
  unsigned* Xc = (unsigned*)d_ws;
  unsigned* Fc = Xc + SZ_X;
  unsigned short* yf = (unsigned short*)(Fc + SZ_F);
  unsigned short* Wt = yf + SZ_Y;

  wconv_kernel<<<dim3(512), dim3(256), 0, stream>>>(W_rc, fc1_w, fc2_w, Wt);
  rfft_kernel<<<dim3(NB * 8), dim3(512), 0, stream>>>(x, Xc);
  freq_mfma_kernel<<<dim3(NF * 2), dim3(512), 0, stream>>>(Xc, W_re, W_im, B_re, B_im, Fc);
  irfft_kernel<<<dim3(NB * 16), dim3(512), 0, stream>>>(Fc, yf);
  mlp_fused_kernel<<<dim3((NB * NT) / 64), dim3(512), 0, stream>>>(x, yf, Wt, fc1_b, fc2_b, out);
}